// Round 2
// baseline (161.322 us; speedup 1.0000x reference)
//
#include <hip/hip_runtime.h>
#include <hip/hip_fp16.h>

#define TPB 256
#define TPBP 512         // k_placeB block
#define TPBS 512         // k_sortB block
#define RNG 128          // nodes per range
#define RSH 7            // log2(RNG)
#define MAXC 1024        // max ranges supported by LDS cursors (N <= 131072)
#define NBP 256          // placing blocks (= #CUs, block-private segments)
#define SEG 48           // per-(range,block) segment capacity (mean 8, +14 sigma)
#define CAPR 4096        // per-range elist capacity (mean ~2046, ~40 sigma)
#define CSH 12           // log2(CAPR)

// ---------------------------------------------------------------------------
// GCN, fully commuted (aggregate only at width 16):
//   hsx = fp16(dinv*x) [N,16];  z = fp16((relu(dinv*agg@W1+b1)*dinv)@Wf) [N,16]
//   out = dinv*(z[n]+sum z[s]) + bf      (Wf = W2@WL, bf = b2@WL + bL)
// R17 build restructure (theory: build-dominated, R16 agg change was neutral):
//   block-PRIVATE per-(range,block) segments -> single edge pass, no global
//   cursor atomics, no gcur memset dispatch (5 -> 4 dispatches).
//   k_placeB: LDS cursors only; writes gbuf[(c*NBP+b)*SEG + pos], dumps counts.
//   k_sortB: scan 256 cell counts -> ragged segment gather into LDS elist ->
//   counting-sort by node -> bucketS + pack + fp16 hsx (unchanged tail).
// Aggregation (R16): 2 lanes/node dwordx4 gathers + v_fma_mix_f32 accumulate.
// Replay-stable: fixed summation shape, no fp atomics (R9 tripwire lesson).
// ---------------------------------------------------------------------------

__device__ inline void fmix2(float& lo, float& hi, unsigned u, float one) {
    // lo += (float)lo16(u); hi += (float)hi16(u)   (exact, fma with 1.0)
    asm("v_fma_mix_f32 %0, %1, %2, %0 op_sel:[0,0,0] op_sel_hi:[1,0,0]"
        : "+v"(lo) : "v"(u), "v"(one));
    asm("v_fma_mix_f32 %0, %1, %2, %0 op_sel:[1,0,0] op_sel_hi:[1,0,0]"
        : "+v"(hi) : "v"(u), "v"(one));
}

__device__ inline void acc8(float a[8], uint4 u, float one) {
    fmix2(a[0], a[1], u.x, one);
    fmix2(a[2], a[3], u.y, one);
    fmix2(a[4], a[5], u.z, one);
    fmix2(a[6], a[7], u.w, one);
}

// single-pass placement into block-private per-range segments.
// Block NBP (extra) instead computes Wf = W2@WL, bf = b2@WL + bL.
__global__ __launch_bounds__(TPBP) void
k_placeB(const int* __restrict__ ei, unsigned* __restrict__ gbuf,
         int* __restrict__ cntB,
         const float* __restrict__ W2, const float* __restrict__ WL,
         const float* __restrict__ b2, const float* __restrict__ bL,
         float* __restrict__ Wf, float* __restrict__ bf,
         int E, int C) {
    int t = threadIdx.x, b = blockIdx.x;
    if (b == NBP) {                                // fused weight-prep block
        for (int idx = t; idx < 1024; idx += TPBP) {
            int k = idx >> 4, o = idx & 15;        // Wf[64][16]
            float s = 0.f;
#pragma unroll 8
            for (int j = 0; j < 128; j++) s += W2[k * 128 + j] * WL[j * 16 + o];
            Wf[idx] = s;
        }
        if (t < 16) {
            float s = bL[t];
            for (int j = 0; j < 128; j++) s += b2[j] * WL[j * 16 + t];
            bf[t] = s;
        }
        return;
    }
    __shared__ int h[MAXC];                        // per-range cursor (private)
    for (int c = t; c < C; c += TPBP) h[c] = 0;
    __syncthreads();
    const int4* s4p = (const int4*)ei;
    const int4* d4p = (const int4*)(ei + E);
    int nq = E >> 2;
    int qpb = (nq + NBP - 1) / NBP;                // int4-quads per block
    int qbase = b * qpb;
    for (int i = t; i < qpb; i += TPBP) {
        int q = qbase + i;
        if (q < nq) {
            int4 s = s4p[q];
            int4 d = d4p[q];
            int c0 = d.x >> RSH, c1 = d.y >> RSH, c2 = d.z >> RSH, c3 = d.w >> RSH;
            int p0 = atomicAdd(&h[c0], 1);
            if (p0 < SEG)
                gbuf[(c0 * NBP + b) * SEG + p0] =
                    ((unsigned)s.x << RSH) | (unsigned)(d.x & (RNG - 1));
            int p1 = atomicAdd(&h[c1], 1);
            if (p1 < SEG)
                gbuf[(c1 * NBP + b) * SEG + p1] =
                    ((unsigned)s.y << RSH) | (unsigned)(d.y & (RNG - 1));
            int p2 = atomicAdd(&h[c2], 1);
            if (p2 < SEG)
                gbuf[(c2 * NBP + b) * SEG + p2] =
                    ((unsigned)s.z << RSH) | (unsigned)(d.z & (RNG - 1));
            int p3 = atomicAdd(&h[c3], 1);
            if (p3 < SEG)
                gbuf[(c3 * NBP + b) * SEG + p3] =
                    ((unsigned)s.w << RSH) | (unsigned)(d.w & (RNG - 1));
        }
    }
    __syncthreads();
    for (int c = t; c < C; c += TPBP)              // dump per-cell counts
        cntB[c * NBP + b] = min(h[c], SEG);
}

// per-range: scan 256 cell counts -> ragged gather into elist -> node-sort ->
// bucketS region + packed CSR + fp16 hsx
__global__ __launch_bounds__(TPBS) void
k_sortB(const unsigned* __restrict__ gbuf, const int* __restrict__ cntB,
        const float* __restrict__ x,
        int* __restrict__ bucketS, unsigned* __restrict__ pack,
        __half2* __restrict__ hsx, int N, int C) {
    __shared__ unsigned elist[CAPR];              // 16 KiB
    __shared__ int scnt[NBP];
    __shared__ int soff[NBP];
    __shared__ int cntN[RNG];
    __shared__ int offs[RNG];
    __shared__ int cur[RNG];
    __shared__ float sdi[RNG];
    __shared__ int mTot;
    int t = threadIdx.x, r = blockIdx.x;
    if (t < RNG) cntN[t] = 0;
    if (t < NBP) {
        int v = cntB[r * NBP + t];
        scnt[t] = v;
        soff[t] = v;
    }
    __syncthreads();
    for (int off = 1; off < NBP; off <<= 1) {     // Hillis-Steele inclusive scan
        int v = 0;
        if (t < NBP && t >= off) v = soff[t - off];
        __syncthreads();
        if (t < NBP) soff[t] += v;
        __syncthreads();
    }
    if (t == NBP - 1) mTot = min(soff[t], CAPR);
    __syncthreads();
    // ragged copy: 2 threads per segment (even/odd elements) + node counting
    {
        int seg = t >> 1, half = t & 1;
        int len = scnt[seg];
        int dstb = soff[seg] - len;
        const unsigned* sp = gbuf + ((size_t)(r * NBP + seg)) * SEG;
        for (int i = half; i < len; i += 2) {
            int di = dstb + i;
            if (di < CAPR) {
                unsigned p = sp[i];
                elist[di] = p;
                atomicAdd(&cntN[p & (RNG - 1)], 1);
            }
        }
    }
    __syncthreads();
    int m = mTot;
    if (t < RNG) offs[t] = cntN[t];
    __syncthreads();
    for (int off = 1; off < RNG; off <<= 1) {     // scan per-node counts
        int v = 0;
        if (t < RNG && t >= off) v = offs[t - off];
        __syncthreads();
        if (t < RNG) offs[t] += v;
        __syncthreads();
    }
    if (t < RNG) {
        int ex = offs[t] - cntN[t];               // exclusive
        cur[t] = ex;
        sdi[t] = rsqrtf((float)cntN[t] + 1.0f);   // +1 self-loop
        int n = r * RNG + t;
        if (n < N) pack[n] = ((unsigned)ex << 16) | (unsigned)cntN[t];
    }
    __syncthreads();
    int rbase = r << CSH;
    for (int i = t; i < m; i += TPBS) {
        unsigned p = elist[i];
        int pos = rbase + atomicAdd(&cur[p & (RNG - 1)], 1);
        bucketS[pos] = (int)(p >> RSH);
    }
    // fused: hsx[n][:] = fp16(dinv[n] * x[n][:]) — 128 nodes x 8 half2
    for (int idx = t; idx < RNG * 8; idx += TPBS) {
        int ln = idx >> 3, f2 = idx & 7;
        int n = r * RNG + ln;
        if (n < N) {
            float2 xv = ((const float2*)x)[(size_t)n * 8 + f2];
            float dn = sdi[ln];
            hsx[(size_t)n * 8 + f2] = __floats2half2_rn(xv.x * dn, xv.y * dn);
        }
    }
}

// layer 1 + projection: nodes-in-lane gather (32 nodes/wave, dwordx4),
// register weights, fma_mix accumulate
__global__ void k_l1f(const int* __restrict__ bucketS, const unsigned* __restrict__ pack,
                      const uint4* __restrict__ hsx, const float* __restrict__ W1,
                      const float* __restrict__ b1, const float* __restrict__ Wf,
                      __half2* __restrict__ z, int N) {
    __shared__ __align__(16) float agg[4][32][16];   // [wave][node][feat] 8 KiB
    __shared__ __align__(16) float vrow[4][64];
    int t = threadIdx.x, wid = t >> 6, lane = t & 63;
    int part = lane >> 4, o = lane & 15;
    // register weights: lane j holds W1[:,j]; lane (part,o) holds Wf[part*16+j][o]
    float w1c[16], wfc[16];
#pragma unroll
    for (int k = 0; k < 16; k++) w1c[k] = W1[k * 64 + lane];
#pragma unroll
    for (int j = 0; j < 16; j++) wfc[j] = Wf[(part * 16 + j) * 16 + o];
    float b1v = b1[lane];
    float one = 1.0f;
    int nodeG = (blockIdx.x * 4 + wid) * 32;      // 32 nodes per wave
    // gather: lane (n2,q) owns node nodeG+n2, half q (16B of the 32B row)
    int n2 = lane >> 1, q = lane & 1;
    int n = nodeG + n2;
    bool valid = n < N;
    int base = 0, d = 0;
    if (valid) {
        unsigned p = pack[n];
        base = ((n >> RSH) << CSH) + (int)(p >> 16);
        d = (int)(p & 0xFFFF);
    }
    float a[8] = {0.f, 0.f, 0.f, 0.f, 0.f, 0.f, 0.f, 0.f};
    if (valid) acc8(a, hsx[(size_t)n * 2 + q], one);   // self-loop
    int k = 0;
    for (; k + 3 < d; k += 4) {                   // 4 gathers in flight/lane
        int s0 = bucketS[base + k];
        int s1 = bucketS[base + k + 1];
        int s2 = bucketS[base + k + 2];
        int s3 = bucketS[base + k + 3];
        uint4 u0 = hsx[(size_t)s0 * 2 + q];
        uint4 u1 = hsx[(size_t)s1 * 2 + q];
        uint4 u2 = hsx[(size_t)s2 * 2 + q];
        uint4 u3 = hsx[(size_t)s3 * 2 + q];
        acc8(a, u0, one);
        acc8(a, u1, one);
        acc8(a, u2, one);
        acc8(a, u3, one);
    }
    for (; k + 1 < d; k += 2) {
        int s0 = bucketS[base + k];
        int s1 = bucketS[base + k + 1];
        uint4 u0 = hsx[(size_t)s0 * 2 + q];
        uint4 u1 = hsx[(size_t)s1 * 2 + q];
        acc8(a, u0, one);
        acc8(a, u1, one);
    }
    if (k < d) acc8(a, hsx[(size_t)bucketS[base + k] * 2 + q], one);
    *(float4*)&agg[wid][n2][q * 8]     = make_float4(a[0], a[1], a[2], a[3]);
    *(float4*)&agg[wid][n2][q * 8 + 4] = make_float4(a[4], a[5], a[6], a[7]);
    // epilogue: 32 nodes batched; agg/vrow same-wave LDS roundtrips (b128)
    const float4* avp = (const float4*)agg[wid];
    const float4* vrp = (const float4*)vrow[wid];
#pragma unroll 4
    for (int nn = 0; nn < 32; nn++) {
        int node = nodeG + nn;
        if (node >= N) break;                     // wave-uniform
        float dn = rsqrtf((float)__shfl(d, nn * 2) + 1.0f);  // deg from owner lane
        float4 A0 = avp[nn * 4 + 0], A1 = avp[nn * 4 + 1];
        float4 A2 = avp[nn * 4 + 2], A3 = avp[nn * 4 + 3];
        float av[16] = {A0.x, A0.y, A0.z, A0.w, A1.x, A1.y, A1.z, A1.w,
                        A2.x, A2.y, A2.z, A2.w, A3.x, A3.y, A3.z, A3.w};
        float v = 0.f;
#pragma unroll
        for (int kk = 0; kk < 16; kk++) v += av[kk] * w1c[kk];
        v = fmaxf(dn * v + b1v, 0.f) * dn;        // lane j holds v_j
        vrow[wid][lane] = v;
        float4 V0 = vrp[part * 4 + 0], V1 = vrp[part * 4 + 1];
        float4 V2 = vrp[part * 4 + 2], V3 = vrp[part * 4 + 3];
        float vv[16] = {V0.x, V0.y, V0.z, V0.w, V1.x, V1.y, V1.z, V1.w,
                        V2.x, V2.y, V2.z, V2.w, V3.x, V3.y, V3.z, V3.w};
        float s = 0.f;
#pragma unroll
        for (int j = 0; j < 16; j++) s += vv[j] * wfc[j];
        s += __shfl_xor(s, 16);
        s += __shfl_xor(s, 32);                   // all lanes: z_o, o=lane&15
        float pv = __shfl(s, lane | 1);
        if (part == 0 && !(lane & 1))
            z[(size_t)node * 8 + (o >> 1)] = __floats2half2_rn(s, pv);
    }
}

// layer 2 aggregation of z + bias: pure nodes-in-lane gather (32 nodes/wave)
__global__ void k_l3(const int* __restrict__ bucketS, const unsigned* __restrict__ pack,
                     const uint4* __restrict__ z, const float* __restrict__ bfv,
                     float* __restrict__ out, int N) {
    int t = threadIdx.x, wid = t >> 6, lane = t & 63;
    int n2 = lane >> 1, q = lane & 1;
    int n = (blockIdx.x * 4 + wid) * 32 + n2;
    if (n >= N) return;
    float one = 1.0f;
    float4 bq0 = ((const float4*)bfv)[q * 2];
    float4 bq1 = ((const float4*)bfv)[q * 2 + 1];
    unsigned p = pack[n];
    int base = ((n >> RSH) << CSH) + (int)(p >> 16);
    int d = (int)(p & 0xFFFF);
    float a[8] = {0.f, 0.f, 0.f, 0.f, 0.f, 0.f, 0.f, 0.f};
    acc8(a, z[(size_t)n * 2 + q], one);           // self-loop
    int k = 0;
    for (; k + 3 < d; k += 4) {
        int s0 = bucketS[base + k];
        int s1 = bucketS[base + k + 1];
        int s2 = bucketS[base + k + 2];
        int s3 = bucketS[base + k + 3];
        uint4 u0 = z[(size_t)s0 * 2 + q];
        uint4 u1 = z[(size_t)s1 * 2 + q];
        uint4 u2 = z[(size_t)s2 * 2 + q];
        uint4 u3 = z[(size_t)s3 * 2 + q];
        acc8(a, u0, one);
        acc8(a, u1, one);
        acc8(a, u2, one);
        acc8(a, u3, one);
    }
    for (; k + 1 < d; k += 2) {
        int s0 = bucketS[base + k];
        int s1 = bucketS[base + k + 1];
        uint4 u0 = z[(size_t)s0 * 2 + q];
        uint4 u1 = z[(size_t)s1 * 2 + q];
        acc8(a, u0, one);
        acc8(a, u1, one);
    }
    if (k < d) acc8(a, z[(size_t)bucketS[base + k] * 2 + q], one);
    float dn = rsqrtf((float)d + 1.0f);
    float4 r0, r1;
    r0.x = dn * a[0] + bq0.x;  r0.y = dn * a[1] + bq0.y;
    r0.z = dn * a[2] + bq0.z;  r0.w = dn * a[3] + bq0.w;
    r1.x = dn * a[4] + bq1.x;  r1.y = dn * a[5] + bq1.y;
    r1.z = dn * a[6] + bq1.z;  r1.w = dn * a[7] + bq1.w;
    ((float4*)out)[(size_t)n * 4 + q * 2]     = r0;   // wave covers 2 KiB
    ((float4*)out)[(size_t)n * 4 + q * 2 + 1] = r1;
}

extern "C" void kernel_launch(void* const* d_in, const int* in_sizes, int n_in,
                              void* d_out, int out_size, void* d_ws, size_t ws_size,
                              hipStream_t stream) {
    const float* x  = (const float*)d_in[0];
    const int*   ei = (const int*)d_in[1];
    const float* W1 = (const float*)d_in[2];
    const float* b1 = (const float*)d_in[3];
    const float* W2 = (const float*)d_in[4];
    const float* b2 = (const float*)d_in[5];
    const float* WL = (const float*)d_in[6];
    const float* bL = (const float*)d_in[7];
    float* out = (float*)d_out;

    const int N  = in_sizes[0] / 16;       // 100000
    const int E  = in_sizes[1] / 2;        // 1600000
    const int C  = (N + RNG - 1) >> RSH;   // 782 ranges

    // ws ints: gbuf[C*NBP*SEG] | cntB[C*NBP] | bucketS[C<<CSH] | pack[N] | pad
    //    then: Wf[1024] f32 | bf[16] | pad16B | hsx[8N] half2 | z[8N] half2
    int* wsi        = (int*)d_ws;
    unsigned* gbuf  = (unsigned*)wsi;                     // 9.61 M dwords
    int* cntB       = wsi + (size_t)C * NBP * SEG;        // 200 K dwords
    int* bucketS    = cntB + (size_t)C * NBP;             // 3.2 M dwords
    unsigned* pack  = (unsigned*)(bucketS + ((size_t)C << CSH));
    size_t off      = (size_t)C * NBP * SEG + (size_t)C * NBP
                    + ((size_t)C << CSH) + N;
    off = (off + 3) & ~(size_t)3;
    float* Wf    = (float*)(wsi + off);
    float* bf    = Wf + 1024;
    off = off + 1024 + 16;
    off = (off + 3) & ~(size_t)3;                 // 16B-align fp16 section
    __half2* hsx = (__half2*)(wsi + off);         // 8N half2
    __half2* z   = (__half2*)(wsi + off + (size_t)8 * N);

    // ---- single-pass block-private placement + fused Wf/bf block ----
    k_placeB<<<NBP + 1, TPBP, 0, stream>>>(ei, gbuf, cntB, W2, WL, b2, bL, Wf, bf, E, C);

    // ---- per-range segment-gather + node sort -> region CSR + pack + hsx ----
    k_sortB<<<C, TPBS, 0, stream>>>(gbuf, cntB, x, bucketS, pack, hsx, N, C);

    // ---- layer 1 + projection -> z fp16 [N,16] ----
    const int NBLK = (N + 127) / 128;             // 128 nodes per block (32/wave)
    k_l1f<<<NBLK, TPB, 0, stream>>>(bucketS, pack, (const uint4*)hsx, W1, b1, Wf, z, N);

    // ---- layer 2 aggregation + bias -> out ----
    k_l3<<<NBLK, TPB, 0, stream>>>(bucketS, pack, (const uint4*)z, bf, out, N);
}

// Round 4
// 152.632 us; speedup vs baseline: 1.0569x; 1.0569x over previous
//
#include <hip/hip_runtime.h>
#include <hip/hip_fp16.h>

#define TPB 256
#define TPBP 1024        // k_place block (16 waves)
#define TPBS 512         // k_sort2 block
#define RNG 128          // nodes per range
#define RSH 7            // log2(RNG)
#define MAXC 1024        // max ranges supported by LDS hist (N <= 131072)
#define EPB 8192         // edges per block in place (chunk ~10.5 edges)
#define CAPR 4096        // per-range region capacity (mean ~2046, ~40 sigma)
#define CSH 12           // log2(CAPR)

// ---------------------------------------------------------------------------
// GCN, fully commuted (aggregate only at width 16):
//   hsx = fp16(dinv*x) [N,16];  z = fp16((relu(dinv*agg@W1+b1)*dinv)@Wf) [N,16]
//   out = dinv*(z[n]+sum z[s]) + bf      (Wf = W2@WL, bf = b2@WL + bL)
// R19: RESTORE of the proven R0 pipeline (149.7/152.5 us) after R18's
//   cooperative-launch hang (graph capture drops the cooperative property ->
//   grid.sync deadlock on replay). Do NOT use hipLaunchCooperativeKernel or
//   software grid barriers in this harness.
// Session evidence: H1 (dispatch overhead) falsified by R17 (-1 dispatch,
//   slower); H2 stands: timed window contains ~3x 256MiB poison fills
//   (~44us each @ ~76% HBM peak) = ~132us fixed floor; our 5 dispatches sum
//   to ~20us, near the gather/build arithmetic floor.
// Replay-stable: fixed summation shape, no fp atomics (R9 tripwire lesson).
// ---------------------------------------------------------------------------

__device__ inline void acc4(float a[4], uint2 u) {
    __half2 h0 = *(__half2*)&u.x, h1 = *(__half2*)&u.y;
    float2 f0 = __half22float2(h0), f1 = __half22float2(h1);
    a[0] += f0.x; a[1] += f0.y; a[2] += f1.x; a[3] += f1.y;
}

// place packed (src<<7 | dst&127) into per-range fixed regions; chunk
// reservation. Block NB (extra) instead computes Wf = W2@WL, bf = b2@WL + bL.
__global__ __launch_bounds__(TPBP) void
k_place(const int* __restrict__ ei, int* __restrict__ gcur,
        unsigned* __restrict__ gbuf,
        const float* __restrict__ W2, const float* __restrict__ WL,
        const float* __restrict__ b2, const float* __restrict__ bL,
        float* __restrict__ Wf, float* __restrict__ bf,
        int E, int C, int NB) {
    int t = threadIdx.x, b = blockIdx.x;
    if (b == NB) {                                 // fused weight-prep block
        int k = t >> 4, o = t & 15;                // t in [0,1024) = 64*16
        if (k < 64) {
            float s = 0.f;
#pragma unroll 8
            for (int j = 0; j < 128; j++) s += W2[k * 128 + j] * WL[j * 16 + o];
            Wf[t] = s;
        }
        if (t < 16) {
            float s = bL[t];
            for (int j = 0; j < 128; j++) s += b2[j] * WL[j * 16 + t];
            bf[t] = s;
        }
        return;
    }
    __shared__ int h[MAXC];
    for (int c = t; c < C; c += TPBP) h[c] = 0;
    __syncthreads();
    const int4* s4p = (const int4*)ei;
    const int4* d4p = (const int4*)(ei + E);
    int nq = E >> 2;
    int qbase = b * (EPB / 4);
#pragma unroll
    for (int it = 0; it < EPB / (4 * TPBP); it++) {  // pass 1: count
        int q = qbase + it * TPBP + t;
        if (q < nq) {
            int4 d = d4p[q];
            atomicAdd(&h[d.x >> RSH], 1);
            atomicAdd(&h[d.y >> RSH], 1);
            atomicAdd(&h[d.z >> RSH], 1);
            atomicAdd(&h[d.w >> RSH], 1);
        }
    }
    __syncthreads();
    for (int c = t; c < C; c += TPBP) {           // reserve chunk per range
        int v = h[c];
        if (v) h[c] = (c << CSH) + atomicAdd(&gcur[c], v);   // absolute cursor
    }
    __syncthreads();
#pragma unroll
    for (int it = 0; it < EPB / (4 * TPBP); it++) {  // pass 2: chunked place
        int q = qbase + it * TPBP + t;
        if (q < nq) {
            int4 s = s4p[q];
            int4 d = d4p[q];
            int c0 = d.x >> RSH, c1 = d.y >> RSH, c2 = d.z >> RSH, c3 = d.w >> RSH;
            int p0 = atomicAdd(&h[c0], 1);
            if (p0 < ((c0 + 1) << CSH))
                gbuf[p0] = ((unsigned)s.x << RSH) | (unsigned)(d.x & (RNG - 1));
            int p1 = atomicAdd(&h[c1], 1);
            if (p1 < ((c1 + 1) << CSH))
                gbuf[p1] = ((unsigned)s.y << RSH) | (unsigned)(d.y & (RNG - 1));
            int p2 = atomicAdd(&h[c2], 1);
            if (p2 < ((c2 + 1) << CSH))
                gbuf[p2] = ((unsigned)s.z << RSH) | (unsigned)(d.z & (RNG - 1));
            int p3 = atomicAdd(&h[c3], 1);
            if (p3 < ((c3 + 1) << CSH))
                gbuf[p3] = ((unsigned)s.w << RSH) | (unsigned)(d.w & (RNG - 1));
        }
    }
}

// per-range node-sort (via LDS elist) -> bucketS region + packed CSR + hsx
__global__ __launch_bounds__(TPBS) void
k_sort2(const unsigned* __restrict__ gbuf, const int* __restrict__ gcur,
        const float* __restrict__ x,
        int* __restrict__ bucketS, unsigned* __restrict__ pack,
        __half2* __restrict__ hsx, int N, int C) {
    __shared__ unsigned elist[CAPR];              // 16 KiB
    __shared__ int cnt[RNG];
    __shared__ int offs[RNG];
    __shared__ int cur[RNG];
    __shared__ float sdi[RNG];
    int t = threadIdx.x, r = blockIdx.x;
    if (t < RNG) cnt[t] = 0;
    __syncthreads();
    int m = min(gcur[r], CAPR);
    const unsigned* src = gbuf + ((size_t)r << CSH);
    for (int i = t; i < m; i += TPBS) {           // single global read of region
        unsigned p = src[i];
        elist[i] = p;
        atomicAdd(&cnt[p & (RNG - 1)], 1);
    }
    __syncthreads();
    if (t < RNG) offs[t] = cnt[t];
    __syncthreads();
    for (int off = 1; off < RNG; off <<= 1) {     // Hillis-Steele inclusive scan
        int v = 0;
        if (t < RNG && t >= off) v = offs[t - off];
        __syncthreads();
        if (t < RNG) offs[t] += v;
        __syncthreads();
    }
    if (t < RNG) {
        int ex = offs[t] - cnt[t];                // exclusive
        cur[t] = ex;
        sdi[t] = rsqrtf((float)cnt[t] + 1.0f);    // +1 self-loop
        int n = r * RNG + t;
        if (n < N) pack[n] = ((unsigned)ex << 16) | (unsigned)cnt[t];
    }
    __syncthreads();
    int rbase = r << CSH;
    for (int i = t; i < m; i += TPBS) {
        unsigned p = elist[i];
        int pos = rbase + atomicAdd(&cur[p & (RNG - 1)], 1);
        bucketS[pos] = (int)(p >> RSH);
    }
    // fused: hsx[n][:] = fp16(dinv[n] * x[n][:]) — 128 nodes x 8 half2
    for (int idx = t; idx < RNG * 8; idx += TPBS) {
        int ln = idx >> 3, f2 = idx & 7;
        int n = r * RNG + ln;
        if (n < N) {
            float2 xv = ((const float2*)x)[(size_t)n * 8 + f2];
            float dn = sdi[ln];
            hsx[(size_t)n * 8 + f2] = __floats2half2_rn(xv.x * dn, xv.y * dn);
        }
    }
}

// layer 1 + projection: nodes-in-lane gather (16 nodes/wave), register weights
__global__ void k_l1f(const int* __restrict__ bucketS, const unsigned* __restrict__ pack,
                      const uint2* __restrict__ hsx, const float* __restrict__ W1,
                      const float* __restrict__ b1, const float* __restrict__ Wf,
                      __half2* __restrict__ z, int N) {
    __shared__ __align__(16) float agg[4][16][16];   // [wave][node][feat]
    __shared__ __align__(16) float vrow[4][64];
    int t = threadIdx.x, wid = t >> 6, lane = t & 63;
    int part = lane >> 4, o = lane & 15;
    // register weights: lane j holds W1[:,j]; lane (part,o) holds Wf[part*16+j][o]
    float w1c[16], wfc[16];
#pragma unroll
    for (int k = 0; k < 16; k++) w1c[k] = W1[k * 64 + lane];
#pragma unroll
    for (int j = 0; j < 16; j++) wfc[j] = Wf[(part * 16 + j) * 16 + o];
    float b1v = b1[lane];
    int nodeG = (blockIdx.x * 4 + wid) * 16;      // 16 nodes per wave
    // gather: lane (n4,q) owns node nodeG+n4, slot q (8B of the 32B row)
    int n4 = lane >> 2, q = lane & 3;
    int n = nodeG + n4;
    bool valid = n < N;
    int base = 0, d = 0;
    if (valid) {
        unsigned p = pack[n];
        base = ((n >> RSH) << CSH) + (int)(p >> 16);
        d = (int)(p & 0xFFFF);
    }
    float a[4] = {0.f, 0.f, 0.f, 0.f};
    if (valid) acc4(a, hsx[(size_t)n * 4 + q]);   // self-loop
    int k = 0;
    for (; k + 1 < d; k += 2) {                   // 2 chains/lane, 128/wave
        int s0 = bucketS[base + k];
        int s1 = bucketS[base + k + 1];
        uint2 u0 = hsx[(size_t)s0 * 4 + q];
        uint2 u1 = hsx[(size_t)s1 * 4 + q];
        acc4(a, u0);
        acc4(a, u1);
    }
    if (k < d) acc4(a, hsx[(size_t)bucketS[base + k] * 4 + q]);
    *(float4*)&agg[wid][n4][q * 4] = make_float4(a[0], a[1], a[2], a[3]);
    // epilogue: 16 nodes batched; agg/vrow same-wave LDS roundtrips (b128)
    const float4* avp = (const float4*)agg[wid];
    const float4* vrp = (const float4*)vrow[wid];
#pragma unroll 4
    for (int nn = 0; nn < 16; nn++) {
        int node = nodeG + nn;
        if (node >= N) break;                     // wave-uniform
        float dn = rsqrtf((float)__shfl(d, nn * 4) + 1.0f);  // deg from owner lane
        float4 A0 = avp[nn * 4 + 0], A1 = avp[nn * 4 + 1];
        float4 A2 = avp[nn * 4 + 2], A3 = avp[nn * 4 + 3];
        float av[16] = {A0.x, A0.y, A0.z, A0.w, A1.x, A1.y, A1.z, A1.w,
                        A2.x, A2.y, A2.z, A2.w, A3.x, A3.y, A3.z, A3.w};
        float v = 0.f;
#pragma unroll
        for (int kk = 0; kk < 16; kk++) v += av[kk] * w1c[kk];
        v = fmaxf(dn * v + b1v, 0.f) * dn;        // lane j holds v_j
        vrow[wid][lane] = v;
        float4 V0 = vrp[part * 4 + 0], V1 = vrp[part * 4 + 1];
        float4 V2 = vrp[part * 4 + 2], V3 = vrp[part * 4 + 3];
        float vv[16] = {V0.x, V0.y, V0.z, V0.w, V1.x, V1.y, V1.z, V1.w,
                        V2.x, V2.y, V2.z, V2.w, V3.x, V3.y, V3.z, V3.w};
        float s = 0.f;
#pragma unroll
        for (int j = 0; j < 16; j++) s += vv[j] * wfc[j];
        s += __shfl_xor(s, 16);
        s += __shfl_xor(s, 32);                   // all lanes: z_o, o=lane&15
        float pv = __shfl(s, lane | 1);
        if (part == 0 && !(lane & 1))
            z[(size_t)node * 8 + (o >> 1)] = __floats2half2_rn(s, pv);
    }
}

// layer 2 aggregation of z + bias: pure nodes-in-lane gather, zero DS ops
__global__ void k_l3(const int* __restrict__ bucketS, const unsigned* __restrict__ pack,
                     const uint2* __restrict__ z, const float* __restrict__ bfv,
                     float* __restrict__ out, int N) {
    int t = threadIdx.x, wid = t >> 6, lane = t & 63;
    int n4 = lane >> 2, q = lane & 3;
    int n = (blockIdx.x * 4 + wid) * 16 + n4;
    if (n >= N) return;
    float4 bq = ((const float4*)bfv)[q];
    unsigned p = pack[n];
    int base = ((n >> RSH) << CSH) + (int)(p >> 16);
    int d = (int)(p & 0xFFFF);
    float a[4] = {0.f, 0.f, 0.f, 0.f};
    acc4(a, z[(size_t)n * 4 + q]);                // self-loop
    int k = 0;
    for (; k + 1 < d; k += 2) {
        int s0 = bucketS[base + k];
        int s1 = bucketS[base + k + 1];
        uint2 u0 = z[(size_t)s0 * 4 + q];
        uint2 u1 = z[(size_t)s1 * 4 + q];
        acc4(a, u0);
        acc4(a, u1);
    }
    if (k < d) acc4(a, z[(size_t)bucketS[base + k] * 4 + q]);
    float dn = rsqrtf((float)d + 1.0f);
    float4 r;
    r.x = dn * a[0] + bq.x;
    r.y = dn * a[1] + bq.y;
    r.z = dn * a[2] + bq.z;
    r.w = dn * a[3] + bq.w;
    ((float4*)out)[(size_t)n * 4 + q] = r;        // fully coalesced
}

extern "C" void kernel_launch(void* const* d_in, const int* in_sizes, int n_in,
                              void* d_out, int out_size, void* d_ws, size_t ws_size,
                              hipStream_t stream) {
    const float* x  = (const float*)d_in[0];
    const int*   ei = (const int*)d_in[1];
    const float* W1 = (const float*)d_in[2];
    const float* b1 = (const float*)d_in[3];
    const float* W2 = (const float*)d_in[4];
    const float* b2 = (const float*)d_in[5];
    const float* WL = (const float*)d_in[6];
    const float* bL = (const float*)d_in[7];
    float* out = (float*)d_out;

    const int N  = in_sizes[0] / 16;       // 100000
    const int E  = in_sizes[1] / 2;        // 1600000
    const int C  = (N + RNG - 1) >> RSH;   // 782 ranges
    const int NB = (E + EPB - 1) / EPB;    // 196 place blocks

    // ws ints: gbuf[C*CAPR] | bucketS[C*CAPR] | gcur[C] | pack[N] | pad
    //    then: Wf[1024] f32 | bf[16] | pad16B | hsx[8N] half2 | z[8N] half2
    int* wsi        = (int*)d_ws;
    unsigned* gbuf  = (unsigned*)wsi;
    int* bucketS    = wsi + ((size_t)C << CSH);
    int* gcur       = bucketS + ((size_t)C << CSH);
    unsigned* pack  = (unsigned*)(gcur + C);
    size_t off      = ((size_t)C << (CSH + 1)) + C + N;
    off = (off + 3) & ~(size_t)3;
    float* Wf    = (float*)(wsi + off);
    float* bf    = Wf + 1024;
    off = off + 1024 + 16;
    off = (off + 3) & ~(size_t)3;                 // 16B-align fp16 section
    __half2* hsx = (__half2*)(wsi + off);         // 8N half2
    __half2* z   = (__half2*)(wsi + off + (size_t)8 * N);

    // zero reservation cursors (3 KB) — replaces the k_wfuse dispatch
    hipMemsetAsync(gcur, 0, (size_t)C * 4, stream);

    // ---- chunked placement into per-range regions + fused Wf/bf block ----
    k_place<<<NB + 1, TPBP, 0, stream>>>(ei, gcur, gbuf, W2, WL, b2, bL, Wf, bf, E, C, NB);

    // ---- per-range node sort -> region CSR + pack + fp16 hsx ----
    k_sort2<<<C, TPBS, 0, stream>>>(gbuf, gcur, x, bucketS, pack, hsx, N, C);

    // ---- layer 1 + projection -> z fp16 [N,16] ----
    const int NBLK = (N + 63) / 64;               // 64 nodes per block (16/wave)
    k_l1f<<<NBLK, TPB, 0, stream>>>(bucketS, pack, (const uint2*)hsx, W1, b1, Wf, z, N);

    // ---- layer 2 aggregation + bias -> out ----
    k_l3<<<NBLK, TPB, 0, stream>>>(bucketS, pack, (const uint2*)z, bf, out, N);
}